// Round 1
// baseline (602.293 us; speedup 1.0000x reference)
//
#include <hip/hip_runtime.h>
#include <math.h>

#define DIMC 256
#define NHEADS 8
#define HDIM 32
#define CPBH 512
#define BB 2
#define NSEQ 2304
#define TAB 9025
#define SPLITS 4
#define MCH (NSEQ/SPLITS)          // 576
#define RTOT (BB*NHEADS*NSEQ)      // 36864

// ---------------- CPB MLP: tabT[h][t] = (relu(table@W1^T+b1)@W2^T+b2)[t][h] ----------------
__global__ void cpb_kernel(const float* __restrict__ tbl, const float* __restrict__ W1,
                           const float* __restrict__ b1, const float* __restrict__ W2,
                           const float* __restrict__ b2, float* __restrict__ tabT) {
  int t = blockIdx.x * 256 + threadIdx.x;
  if (t >= TAB) return;
  float c0 = tbl[2*t], c1 = tbl[2*t+1];
  float acc[NHEADS];
#pragma unroll
  for (int h = 0; h < NHEADS; ++h) acc[h] = 0.f;
  for (int j = 0; j < CPBH; ++j) {
    float hid = fmaxf(fmaf(c0, W1[2*j], fmaf(c1, W1[2*j+1], b1[j])), 0.f);
#pragma unroll
    for (int h = 0; h < NHEADS; ++h) acc[h] = fmaf(hid, W2[h*CPBH + j], acc[h]);
  }
#pragma unroll
  for (int h = 0; h < NHEADS; ++h) tabT[h*TAB + t] = acc[h] + b2[h];
}

// ---------------- fp32 GEMM: C[M,Nn] = A[M,K] @ W[Nn,K]^T + bias ----------------
__launch_bounds__(256)
__global__ void gemm_tn(const float* __restrict__ A, const float* __restrict__ W,
                        const float* __restrict__ bias, float* __restrict__ C,
                        int M, int Nn, int K) {
  __shared__ float As[16][72];   // [k][m], pad 72 keeps float4 alignment, 2-4 way store conflict only
  __shared__ float Bs[16][72];   // [k][n]
  int tid = threadIdx.x;
  int tn = tid & 15, tm = tid >> 4;
  int n0 = blockIdx.x * 64, m0 = blockIdx.y * 64;
  float acc[4][4] = {};
  for (int k0 = 0; k0 < K; k0 += 16) {
#pragma unroll
    for (int l = 0; l < 4; ++l) {
      int t = tid + l * 256;
      int r = t >> 4, c = t & 15;
      As[c][r] = A[(size_t)(m0 + r) * K + k0 + c];
      Bs[c][r] = W[(size_t)(n0 + r) * K + k0 + c];
    }
    __syncthreads();
#pragma unroll
    for (int kk = 0; kk < 16; ++kk) {
      float4 a = *(const float4*)&As[kk][tm * 4];
      float4 b = *(const float4*)&Bs[kk][tn * 4];
      float av[4] = {a.x, a.y, a.z, a.w};
      float bv[4] = {b.x, b.y, b.z, b.w};
#pragma unroll
      for (int i = 0; i < 4; ++i)
#pragma unroll
        for (int j = 0; j < 4; ++j)
          acc[i][j] = fmaf(av[i], bv[j], acc[i][j]);
    }
    __syncthreads();
  }
  float bv[4];
#pragma unroll
  for (int j = 0; j < 4; ++j) bv[j] = bias[n0 + tn * 4 + j];
#pragma unroll
  for (int i = 0; i < 4; ++i) {
    int m = m0 + tm * 4 + i;
    float4 o;
    o.x = acc[i][0] + bv[0];
    o.y = acc[i][1] + bv[1];
    o.z = acc[i][2] + bv[2];
    o.w = acc[i][3] + bv[3];
    *(float4*)&C[(size_t)m * Nn + n0 + tn * 4] = o;
  }
}

// ---------------- split qkv -> qn (normalized+embed+scaled), kn (normalized), v ----------------
__global__ void prep_kernel(const float* __restrict__ qkv, const float* __restrict__ temp,
                            const float* __restrict__ sls, const float* __restrict__ qe,
                            float* __restrict__ qn, float* __restrict__ kn, float* __restrict__ vv) {
  int r = blockIdx.x * 256 + threadIdx.x;
  if (r >= RTOT) return;
  int n = r % NSEQ; int bh = r / NSEQ; int h = bh % NHEADS; int b = bh / NHEADS;
  const float* base = qkv + (size_t)(b * NSEQ + n) * (3 * DIMC);
  float q[HDIM], k[HDIM], vl[HDIM];
#pragma unroll
  for (int i = 0; i < HDIM; i += 4) {
    *(float4*)&q[i]  = *(const float4*)&base[h * HDIM + i];
    *(float4*)&k[i]  = *(const float4*)&base[DIMC + h * HDIM + i];
    *(float4*)&vl[i] = *(const float4*)&base[2 * DIMC + h * HDIM + i];
  }
  float sq = 0.f, sk = 0.f;
#pragma unroll
  for (int i = 0; i < HDIM; ++i) { sq = fmaf(q[i], q[i], sq); sk = fmaf(k[i], k[i], sk); }
  float invq = 1.f / fmaxf(sqrtf(sq), 1e-12f);
  float invk = 1.f / fmaxf(sqrtf(sk), 1e-12f);
  float scale = log1pf(expf(temp[h])) * sls[0];
  size_t o = (size_t)r * HDIM;
#pragma unroll
  for (int i = 0; i < HDIM; i += 4) {
    float4 t4;
    t4.x = (q[i+0] * invq + qe[h*HDIM + i+0]) * scale;
    t4.y = (q[i+1] * invq + qe[h*HDIM + i+1]) * scale;
    t4.z = (q[i+2] * invq + qe[h*HDIM + i+2]) * scale;
    t4.w = (q[i+3] * invq + qe[h*HDIM + i+3]) * scale;
    *(float4*)&qn[o + i] = t4;
    float4 k4; k4.x = k[i]*invk; k4.y = k[i+1]*invk; k4.z = k[i+2]*invk; k4.w = k[i+3]*invk;
    *(float4*)&kn[o + i] = k4;
    *(float4*)&vv[o + i] = *(const float4*)&vl[i];
  }
}

// ---------------- flash attention: lane = q-row, wave-uniform k/v broadcast, m-split ----------------
__launch_bounds__(64)
__global__ void attn_kernel(const float* __restrict__ qn, const float* __restrict__ kn,
                            const float* __restrict__ vv, const float* __restrict__ tabT,
                            const int* __restrict__ idx, float* __restrict__ pO,
                            float* __restrict__ pM, float* __restrict__ pL) {
  int lane = threadIdx.x;
  int s = blockIdx.x;
  int yb = blockIdx.y;
  int nb = yb % (NSEQ / 64); int bh = yb / (NSEQ / 64); int h = bh % NHEADS;
  int n = nb * 64 + lane;
  size_t row = (size_t)bh * NSEQ + n;
  float q[HDIM];
#pragma unroll
  for (int i = 0; i < HDIM; i += 4) *(float4*)&q[i] = *(const float4*)&qn[row * HDIM + i];
  const float* tb = tabT + h * TAB;
  const int* irow = idx + (size_t)n * NSEQ;
  size_t kvbase = (size_t)bh * NSEQ;
  float M = -INFINITY, L = 0.f;
  float o[HDIM];
#pragma unroll
  for (int i = 0; i < HDIM; ++i) o[i] = 0.f;

  for (int mt = s * MCH; mt < (s + 1) * MCH; mt += 16) {
    int ib[16];
#pragma unroll
    for (int j = 0; j < 4; ++j) *(int4*)&ib[4 * j] = *(const int4*)&irow[mt + 4 * j];
    float sc[16];
#pragma unroll
    for (int j = 0; j < 16; ++j) {
      const float* kr = kn + (kvbase + mt + j) * HDIM;  // wave-uniform address
      float d0 = 0.f, d1 = 0.f, d2 = 0.f, d3 = 0.f;
#pragma unroll
      for (int i = 0; i < HDIM; i += 4) {
        d0 = fmaf(q[i+0], kr[i+0], d0);
        d1 = fmaf(q[i+1], kr[i+1], d1);
        d2 = fmaf(q[i+2], kr[i+2], d2);
        d3 = fmaf(q[i+3], kr[i+3], d3);
      }
      sc[j] = (d0 + d1) + (d2 + d3) + tb[ib[j]];
    }
    float cm = sc[0];
#pragma unroll
    for (int j = 1; j < 16; ++j) cm = fmaxf(cm, sc[j]);
    if (cm > M) {                       // amortized rescale (once per 16-chunk at most)
      float alpha = __expf(M - cm);     // M=-inf first time -> alpha=0, zeroes state
      L *= alpha;
#pragma unroll
      for (int i = 0; i < HDIM; ++i) o[i] *= alpha;
      M = cm;
    }
#pragma unroll
    for (int j = 0; j < 16; ++j) {
      float p = __expf(sc[j] - M);
      L += p;
      const float* vr = vv + (kvbase + mt + j) * HDIM;  // wave-uniform address
#pragma unroll
      for (int i = 0; i < HDIM; ++i) o[i] = fmaf(p, vr[i], o[i]);
    }
  }
  size_t pr = (size_t)s * RTOT + row;
  pM[pr] = M;
  pL[pr] = L;
#pragma unroll
  for (int i = 0; i < HDIM; i += 4) *(float4*)&pO[pr * HDIM + i] = *(const float4*)&o[i];
}

// ---------------- merge m-splits, write (b,n,h*d) layout for proj ----------------
__global__ void merge_kernel(const float* __restrict__ pO, const float* __restrict__ pM,
                             const float* __restrict__ pL, float* __restrict__ ao) {
  int r = blockIdx.x * 256 + threadIdx.x;
  if (r >= RTOT) return;
  float M = -INFINITY;
#pragma unroll
  for (int sp = 0; sp < SPLITS; ++sp) M = fmaxf(M, pM[(size_t)sp * RTOT + r]);
  float w[SPLITS]; float L = 0.f;
#pragma unroll
  for (int sp = 0; sp < SPLITS; ++sp) {
    w[sp] = __expf(pM[(size_t)sp * RTOT + r] - M);
    L = fmaf(pL[(size_t)sp * RTOT + r], w[sp], L);
  }
  float inv = 1.f / L;
  int n = r % NSEQ; int bh = r / NSEQ; int h = bh % NHEADS; int b = bh / NHEADS;
  float* dst = ao + (size_t)(b * NSEQ + n) * DIMC + h * HDIM;
#pragma unroll
  for (int i = 0; i < HDIM; ++i) {
    float acc = 0.f;
#pragma unroll
    for (int sp = 0; sp < SPLITS; ++sp)
      acc = fmaf(pO[((size_t)sp * RTOT + r) * HDIM + i], w[sp], acc);
    dst[i] = acc * inv;
  }
}

extern "C" void kernel_launch(void* const* d_in, const int* in_sizes, int n_in,
                              void* d_out, int out_size, void* d_ws, size_t ws_size,
                              hipStream_t stream) {
  const float* x    = (const float*)d_in[0];
  const int*   idx  = (const int*)d_in[1];
  const float* tbl  = (const float*)d_in[2];
  const float* sls  = (const float*)d_in[3];
  /* d_in[4] padding_mask: unused by reference */
  const float* Wqkv = (const float*)d_in[5];
  const float* bqkv = (const float*)d_in[6];
  const float* temp = (const float*)d_in[7];
  const float* qe   = (const float*)d_in[8];
  const float* Wp   = (const float*)d_in[9];
  const float* bp   = (const float*)d_in[10];
  const float* W1   = (const float*)d_in[11];
  const float* b1   = (const float*)d_in[12];
  const float* W2   = (const float*)d_in[13];
  const float* b2   = (const float*)d_in[14];

  float* ws   = (float*)d_ws;
  float* tabT = ws;                      // 72,200 (pad to 72,256)
  float* qkv  = tabT + 72256;            // 4608*768 = 3,538,944
  float* qnb  = qkv + 3538944;           // 1,179,648 each
  float* knb  = qnb + 1179648;
  float* vvb  = knb + 1179648;
  float* ao   = vvb + 1179648;           // 1,179,648
  float* pO   = ao + 1179648;            // 4*36864*32 = 4,718,592
  float* pM   = pO + 4718592;            // 147,456
  float* pL   = pM + 147456;             // 147,456
  float* out  = (float*)d_out;

  cpb_kernel<<<dim3((TAB + 255) / 256), dim3(256), 0, stream>>>(tbl, W1, b1, W2, b2, tabT);
  gemm_tn<<<dim3(12, 72), dim3(256), 0, stream>>>(x, Wqkv, bqkv, qkv, BB * NSEQ, 3 * DIMC, DIMC);
  prep_kernel<<<dim3(RTOT / 256), dim3(256), 0, stream>>>(qkv, temp, sls, qe, qnb, knb, vvb);
  attn_kernel<<<dim3(SPLITS, RTOT / 64), dim3(64), 0, stream>>>(qnb, knb, vvb, tabT, idx, pO, pM, pL);
  merge_kernel<<<dim3(RTOT / 256), dim3(256), 0, stream>>>(pO, pM, pL, ao);
  gemm_tn<<<dim3(4, 72), dim3(256), 0, stream>>>(ao, Wp, bp, out, BB * NSEQ, DIMC, DIMC);
}

// Round 2
// 542.780 us; speedup vs baseline: 1.1096x; 1.1096x over previous
//
#include <hip/hip_runtime.h>
#include <math.h>

#define DIMC 256
#define NHEADS 8
#define HDIM 32
#define CPBH 512
#define BB 2
#define NSEQ 2304
#define TAB 9025
#define RTOT (BB*NHEADS*NSEQ)      // 36864
#define NWAVES 8
#define MW (NSEQ/NWAVES)           // 288 m-values per wave
#define CH 8                       // m-chunk per iteration

// ---------------- CPB MLP: tabT[h][t] ----------------
__global__ void cpb_kernel(const float* __restrict__ tbl, const float* __restrict__ W1,
                           const float* __restrict__ b1, const float* __restrict__ W2,
                           const float* __restrict__ b2, float* __restrict__ tabT) {
  int t = blockIdx.x * 256 + threadIdx.x;
  if (t >= TAB) return;
  float c0 = tbl[2*t], c1 = tbl[2*t+1];
  float acc[NHEADS];
#pragma unroll
  for (int h = 0; h < NHEADS; ++h) acc[h] = 0.f;
  for (int j = 0; j < CPBH; ++j) {
    float hid = fmaxf(fmaf(c0, W1[2*j], fmaf(c1, W1[2*j+1], b1[j])), 0.f);
#pragma unroll
    for (int h = 0; h < NHEADS; ++h) acc[h] = fmaf(hid, W2[h*CPBH + j], acc[h]);
  }
#pragma unroll
  for (int h = 0; h < NHEADS; ++h) tabT[h*TAB + t] = acc[h] + b2[h];
}

// ---------------- transpose idx -> ushort idxT[m][n] ----------------
__global__ void transpose_idx(const int* __restrict__ idx, unsigned short* __restrict__ idxT) {
  __shared__ int tile[32][33];
  int bx = blockIdx.x * 32, by = blockIdx.y * 32;
  int tx = threadIdx.x, ty = threadIdx.y;
#pragma unroll
  for (int k = 0; k < 32; k += 8)
    tile[ty + k][tx] = idx[(size_t)(by + ty + k) * NSEQ + bx + tx];
  __syncthreads();
#pragma unroll
  for (int k = 0; k < 32; k += 8)
    idxT[(size_t)(bx + ty + k) * NSEQ + by + tx] = (unsigned short)tile[tx][ty + k];
}

// ---------------- fp32 GEMM: C[M,Nn] = A[M,K] @ W[Nn,K]^T + bias ----------------
__launch_bounds__(256)
__global__ void gemm_tn(const float* __restrict__ A, const float* __restrict__ W,
                        const float* __restrict__ bias, float* __restrict__ C,
                        int M, int Nn, int K) {
  __shared__ float As[16][72];
  __shared__ float Bs[16][72];
  int tid = threadIdx.x;
  int tn = tid & 15, tm = tid >> 4;
  int n0 = blockIdx.x * 64, m0 = blockIdx.y * 64;
  float acc[4][4] = {};
  for (int k0 = 0; k0 < K; k0 += 16) {
#pragma unroll
    for (int l = 0; l < 4; ++l) {
      int t = tid + l * 256;
      int r = t >> 4, c = t & 15;
      As[c][r] = A[(size_t)(m0 + r) * K + k0 + c];
      Bs[c][r] = W[(size_t)(n0 + r) * K + k0 + c];
    }
    __syncthreads();
#pragma unroll
    for (int kk = 0; kk < 16; ++kk) {
      float4 a = *(const float4*)&As[kk][tm * 4];
      float4 b = *(const float4*)&Bs[kk][tn * 4];
      float av[4] = {a.x, a.y, a.z, a.w};
      float bv[4] = {b.x, b.y, b.z, b.w};
#pragma unroll
      for (int i = 0; i < 4; ++i)
#pragma unroll
        for (int j = 0; j < 4; ++j)
          acc[i][j] = fmaf(av[i], bv[j], acc[i][j]);
    }
    __syncthreads();
  }
  float bv[4];
#pragma unroll
  for (int j = 0; j < 4; ++j) bv[j] = bias[n0 + tn * 4 + j];
#pragma unroll
  for (int i = 0; i < 4; ++i) {
    int m = m0 + tm * 4 + i;
    float4 o;
    o.x = acc[i][0] + bv[0];
    o.y = acc[i][1] + bv[1];
    o.z = acc[i][2] + bv[2];
    o.w = acc[i][3] + bv[3];
    *(float4*)&C[(size_t)m * Nn + n0 + tn * 4] = o;
  }
}

// ---------------- split qkv -> qn, kn, v ----------------
__global__ void prep_kernel(const float* __restrict__ qkv, const float* __restrict__ temp,
                            const float* __restrict__ sls, const float* __restrict__ qe,
                            float* __restrict__ qn, float* __restrict__ kn, float* __restrict__ vv) {
  int r = blockIdx.x * 256 + threadIdx.x;
  if (r >= RTOT) return;
  int n = r % NSEQ; int bh = r / NSEQ; int h = bh % NHEADS; int b = bh / NHEADS;
  const float* base = qkv + (size_t)(b * NSEQ + n) * (3 * DIMC);
  float q[HDIM], k[HDIM], vl[HDIM];
#pragma unroll
  for (int i = 0; i < HDIM; i += 4) {
    *(float4*)&q[i]  = *(const float4*)&base[h * HDIM + i];
    *(float4*)&k[i]  = *(const float4*)&base[DIMC + h * HDIM + i];
    *(float4*)&vl[i] = *(const float4*)&base[2 * DIMC + h * HDIM + i];
  }
  float sq = 0.f, sk = 0.f;
#pragma unroll
  for (int i = 0; i < HDIM; ++i) { sq = fmaf(q[i], q[i], sq); sk = fmaf(k[i], k[i], sk); }
  float invq = 1.f / fmaxf(sqrtf(sq), 1e-12f);
  float invk = 1.f / fmaxf(sqrtf(sk), 1e-12f);
  float scale = log1pf(expf(temp[h])) * sls[0];
  size_t o = (size_t)r * HDIM;
#pragma unroll
  for (int i = 0; i < HDIM; i += 4) {
    float4 t4;
    t4.x = (q[i+0] * invq + qe[h*HDIM + i+0]) * scale;
    t4.y = (q[i+1] * invq + qe[h*HDIM + i+1]) * scale;
    t4.z = (q[i+2] * invq + qe[h*HDIM + i+2]) * scale;
    t4.w = (q[i+3] * invq + qe[h*HDIM + i+3]) * scale;
    *(float4*)&qn[o + i] = t4;
    float4 k4; k4.x = k[i]*invk; k4.y = k[i+1]*invk; k4.z = k[i+2]*invk; k4.w = k[i+3]*invk;
    *(float4*)&kn[o + i] = k4;
    *(float4*)&vv[o + i] = *(const float4*)&vl[i];
  }
}

// ---------------- flash attention: 8 waves/block = 8 m-splits, LDS bias table, in-block merge ----------------
__launch_bounds__(512, 4)
__global__ void attn_kernel(const float* __restrict__ qn, const float* __restrict__ kn,
                            const float* __restrict__ vv, const float* __restrict__ tabT,
                            const unsigned short* __restrict__ idxT, float* __restrict__ ao) {
  __shared__ float tbf[TAB];   // bias table for this head; reused as merge buffer (needs 4*64*34=8704 <= 9025)
  int tid = threadIdx.x;
  int lane = tid & 63;
  int w = __builtin_amdgcn_readfirstlane(tid >> 6);   // wave id, force SGPR so m-addresses stay scalar
  int nb = blockIdx.x;                 // 36 n-tiles
  int bh = blockIdx.y;                 // 16 (b,h)
  int h = bh & (NHEADS - 1); int b = bh >> 3;

  for (int t = tid; t < TAB; t += 512) tbf[t] = tabT[h * TAB + t];

  int n = nb * 64 + lane;
  size_t row = (size_t)bh * NSEQ + n;
  float q[HDIM];
#pragma unroll
  for (int i = 0; i < HDIM; i += 4) *(float4*)&q[i] = *(const float4*)&qn[row * HDIM + i];
  size_t kvbase = (size_t)bh * NSEQ;
  __syncthreads();

  float M = -INFINITY, L = 0.f;
  float o[HDIM];
#pragma unroll
  for (int i = 0; i < HDIM; ++i) o[i] = 0.f;

  int m0 = w * MW;
  for (int mt = m0; mt < m0 + MW; mt += CH) {
    int ib[CH];
#pragma unroll
    for (int j = 0; j < CH; ++j) ib[j] = idxT[(size_t)(mt + j) * NSEQ + n];  // coalesced u16
    float sc[CH];
#pragma unroll
    for (int j = 0; j < CH; ++j) {
      const float* kr = kn + (kvbase + mt + j) * HDIM;   // wave-uniform -> s_load
      float d0 = 0.f, d1 = 0.f, d2 = 0.f, d3 = 0.f;
#pragma unroll
      for (int i = 0; i < HDIM; i += 4) {
        d0 = fmaf(q[i+0], kr[i+0], d0);
        d1 = fmaf(q[i+1], kr[i+1], d1);
        d2 = fmaf(q[i+2], kr[i+2], d2);
        d3 = fmaf(q[i+3], kr[i+3], d3);
      }
      sc[j] = (d0 + d1) + (d2 + d3) + tbf[ib[j]];        // LDS gather
    }
    float cm = sc[0];
#pragma unroll
    for (int j = 1; j < CH; ++j) cm = fmaxf(cm, sc[j]);
    if (cm > M) {
      float alpha = __expf(M - cm);
      L *= alpha;
#pragma unroll
      for (int i = 0; i < HDIM; ++i) o[i] *= alpha;
      M = cm;
    }
#pragma unroll
    for (int j = 0; j < CH; ++j) {
      float p = __expf(sc[j] - M);
      L += p;
      const float* vr = vv + (kvbase + mt + j) * HDIM;   // wave-uniform -> s_load
#pragma unroll
      for (int i = 0; i < HDIM; ++i) o[i] = fmaf(p, vr[i], o[i]);
    }
  }

  __syncthreads();   // everyone done reading tbf; safe to reuse as merge buffer
  float* red = tbf;
#pragma unroll
  for (int step = 4; step >= 1; step >>= 1) {
    if (w >= step && w < 2 * step) {
      float* dst = red + ((size_t)(w - step) * 64 + lane) * 34;
#pragma unroll
      for (int i = 0; i < HDIM; ++i) dst[i] = o[i];
      dst[32] = M; dst[33] = L;
    }
    __syncthreads();
    if (w < step) {
      const float* src = red + ((size_t)w * 64 + lane) * 34;
      float M2 = src[32], L2 = src[33];
      float Mn = fmaxf(M, M2);
      float a1 = __expf(M - Mn), a2 = __expf(M2 - Mn);
      L = L * a1 + L2 * a2;
#pragma unroll
      for (int i = 0; i < HDIM; ++i) o[i] = o[i] * a1 + src[i] * a2;
      M = Mn;
    }
    __syncthreads();
  }

  if (w == 0) {
    float inv = 1.f / L;
    float* dst = ao + (size_t)(b * NSEQ + n) * DIMC + h * HDIM;
#pragma unroll
    for (int i = 0; i < HDIM; i += 4) {
      float4 t4;
      t4.x = o[i+0] * inv; t4.y = o[i+1] * inv; t4.z = o[i+2] * inv; t4.w = o[i+3] * inv;
      *(float4*)&dst[i] = t4;
    }
  }
}

extern "C" void kernel_launch(void* const* d_in, const int* in_sizes, int n_in,
                              void* d_out, int out_size, void* d_ws, size_t ws_size,
                              hipStream_t stream) {
  const float* x    = (const float*)d_in[0];
  const int*   idx  = (const int*)d_in[1];
  const float* tbl  = (const float*)d_in[2];
  const float* sls  = (const float*)d_in[3];
  const float* Wqkv = (const float*)d_in[5];
  const float* bqkv = (const float*)d_in[6];
  const float* temp = (const float*)d_in[7];
  const float* qe   = (const float*)d_in[8];
  const float* Wp   = (const float*)d_in[9];
  const float* bp   = (const float*)d_in[10];
  const float* W1   = (const float*)d_in[11];
  const float* b1   = (const float*)d_in[12];
  const float* W2   = (const float*)d_in[13];
  const float* b2   = (const float*)d_in[14];

  float* ws   = (float*)d_ws;
  float* tabT = ws;                       // 72,256 (72,200 used)
  float* qkv  = tabT + 72256;             // 3,538,944
  float* qnb  = qkv + 3538944;            // 1,179,648
  float* knb  = qnb + 1179648;            // 1,179,648
  float* vvb  = knb + 1179648;            // 1,179,648
  float* ao   = vvb + 1179648;            // 1,179,648
  unsigned short* idxT = (unsigned short*)(ao + 1179648);  // 5,308,416 u16 = 2,654,208 floats
  float* out  = (float*)d_out;

  transpose_idx<<<dim3(NSEQ/32, NSEQ/32), dim3(32, 8), 0, stream>>>(idx, idxT);
  cpb_kernel<<<dim3((TAB + 255) / 256), dim3(256), 0, stream>>>(tbl, W1, b1, W2, b2, tabT);
  gemm_tn<<<dim3(12, 72), dim3(256), 0, stream>>>(x, Wqkv, bqkv, qkv, BB * NSEQ, 3 * DIMC, DIMC);
  prep_kernel<<<dim3(RTOT / 256), dim3(256), 0, stream>>>(qkv, temp, sls, qe, qnb, knb, vvb);
  attn_kernel<<<dim3(NSEQ / 64, BB * NHEADS), dim3(512), 0, stream>>>(qnb, knb, vvb, tabT, idxT, ao);
  gemm_tn<<<dim3(4, 72), dim3(256), 0, stream>>>(ao, Wp, bp, out, BB * NSEQ, DIMC, DIMC);
}

// Round 3
// 352.293 us; speedup vs baseline: 1.7096x; 1.5407x over previous
//
#include <hip/hip_runtime.h>
#include <math.h>

#define DIMC 256
#define NHEADS 8
#define HDIM 32
#define CPBH 512
#define BB 2
#define NSEQ 2304
#define TAB 9025
#define RTOT (BB*NHEADS*NSEQ)      // 36864
#define SPLITS 2
#define MSP (NSEQ/SPLITS)          // 1152 m per split

typedef unsigned short ushort;
typedef __attribute__((ext_vector_type(8))) short short8;
typedef __attribute__((ext_vector_type(4))) float f32x4;

#define MFMA16(a,b,c) __builtin_amdgcn_mfma_f32_16x16x32_bf16((a),(b),(c),0,0,0)

__device__ __forceinline__ ushort f2bf(float x) {          // RNE fp32->bf16
  unsigned u = __float_as_uint(x);
  u += 0x7FFFu + ((u >> 16) & 1u);
  return (ushort)(u >> 16);
}
__device__ __forceinline__ float bf2f(ushort b) {
  return __uint_as_float(((unsigned)b) << 16);
}

// ---------------- CPB MLP: tabT[h][t] ----------------
__global__ void cpb_kernel(const float* __restrict__ tbl, const float* __restrict__ W1,
                           const float* __restrict__ b1, const float* __restrict__ W2,
                           const float* __restrict__ b2, float* __restrict__ tabT) {
  int t = blockIdx.x * 256 + threadIdx.x;
  if (t >= TAB) return;
  float c0 = tbl[2*t], c1 = tbl[2*t+1];
  float acc[NHEADS];
#pragma unroll
  for (int h = 0; h < NHEADS; ++h) acc[h] = 0.f;
  for (int j = 0; j < CPBH; ++j) {
    float hid = fmaxf(fmaf(c0, W1[2*j], fmaf(c1, W1[2*j+1], b1[j])), 0.f);
#pragma unroll
    for (int h = 0; h < NHEADS; ++h) acc[h] = fmaf(hid, W2[h*CPBH + j], acc[h]);
  }
#pragma unroll
  for (int h = 0; h < NHEADS; ++h) tabT[h*TAB + t] = acc[h] + b2[h];
}

// ---------------- fp32 GEMM: C[M,Nn] = A[M,K] @ W[Nn,K]^T + bias ----------------
__launch_bounds__(256)
__global__ void gemm_tn(const float* __restrict__ A, const float* __restrict__ W,
                        const float* __restrict__ bias, float* __restrict__ C,
                        int M, int Nn, int K) {
  __shared__ float As[16][72];
  __shared__ float Bs[16][72];
  int tid = threadIdx.x;
  int tn = tid & 15, tm = tid >> 4;
  int n0 = blockIdx.x * 64, m0 = blockIdx.y * 64;
  float acc[4][4] = {};
  for (int k0 = 0; k0 < K; k0 += 16) {
#pragma unroll
    for (int l = 0; l < 4; ++l) {
      int t = tid + l * 256;
      int r = t >> 4, c = t & 15;
      As[c][r] = A[(size_t)(m0 + r) * K + k0 + c];
      Bs[c][r] = W[(size_t)(n0 + r) * K + k0 + c];
    }
    __syncthreads();
#pragma unroll
    for (int kk = 0; kk < 16; ++kk) {
      float4 a = *(const float4*)&As[kk][tm * 4];
      float4 b = *(const float4*)&Bs[kk][tn * 4];
      float av[4] = {a.x, a.y, a.z, a.w};
      float bv[4] = {b.x, b.y, b.z, b.w};
#pragma unroll
      for (int i = 0; i < 4; ++i)
#pragma unroll
        for (int j = 0; j < 4; ++j)
          acc[i][j] = fmaf(av[i], bv[j], acc[i][j]);
    }
    __syncthreads();
  }
  float bv[4];
#pragma unroll
  for (int j = 0; j < 4; ++j) bv[j] = bias[n0 + tn * 4 + j];
#pragma unroll
  for (int i = 0; i < 4; ++i) {
    int m = m0 + tm * 4 + i;
    float4 o;
    o.x = acc[i][0] + bv[0];
    o.y = acc[i][1] + bv[1];
    o.z = acc[i][2] + bv[2];
    o.w = acc[i][3] + bv[3];
    *(float4*)&C[(size_t)m * Nn + n0 + tn * 4] = o;
  }
}

// ------- prep: qkv -> split-bf16 qhi/qlo/khi/klo [row][32], bf16 vT [bh][d][m] -------
__global__ void prep_kernel(const float* __restrict__ qkv, const float* __restrict__ temp,
                            const float* __restrict__ sls, const float* __restrict__ qe,
                            ushort* __restrict__ qhi, ushort* __restrict__ qlo,
                            ushort* __restrict__ khi, ushort* __restrict__ klo,
                            ushort* __restrict__ vT) {
  int r = blockIdx.x * 256 + threadIdx.x;
  if (r >= RTOT) return;
  int n = r % NSEQ; int bh = r / NSEQ; int h = bh % NHEADS; int b = bh / NHEADS;
  const float* base = qkv + (size_t)(b * NSEQ + n) * (3 * DIMC);
  float q[HDIM], k[HDIM], vl[HDIM];
#pragma unroll
  for (int i = 0; i < HDIM; i += 4) {
    *(float4*)&q[i]  = *(const float4*)&base[h * HDIM + i];
    *(float4*)&k[i]  = *(const float4*)&base[DIMC + h * HDIM + i];
    *(float4*)&vl[i] = *(const float4*)&base[2 * DIMC + h * HDIM + i];
  }
  float sq = 0.f, sk = 0.f;
#pragma unroll
  for (int i = 0; i < HDIM; ++i) { sq = fmaf(q[i], q[i], sq); sk = fmaf(k[i], k[i], sk); }
  float invq = 1.f / fmaxf(sqrtf(sq), 1e-12f);
  float invk = 1.f / fmaxf(sqrtf(sk), 1e-12f);
  float scale = log1pf(expf(temp[h])) * sls[0];
  size_t o = (size_t)r * HDIM;
#pragma unroll
  for (int i = 0; i < HDIM; ++i) {
    float qs = (q[i] * invq + qe[h*HDIM + i]) * scale;
    ushort qh = f2bf(qs);
    qhi[o + i] = qh;
    qlo[o + i] = f2bf(qs - bf2f(qh));
    float ks = k[i] * invk;
    ushort kh = f2bf(ks);
    khi[o + i] = kh;
    klo[o + i] = f2bf(ks - bf2f(kh));
    vT[((size_t)(bh * HDIM + i)) * NSEQ + n] = f2bf(vl[i]);
  }
}

// ---------------- MFMA flash attention: wave = 16 q-rows, m-chunks of 32 ----------------
__launch_bounds__(256)
__global__ void attn_kernel(const ushort* __restrict__ qhi, const ushort* __restrict__ qlo,
                            const ushort* __restrict__ khi, const ushort* __restrict__ klo,
                            const ushort* __restrict__ vT, const float* __restrict__ tabT,
                            const int* __restrict__ idx,
                            float* __restrict__ pO, float* __restrict__ pM, float* __restrict__ pL) {
  __shared__ float tbf[TAB];
  __shared__ __align__(16) ushort pbuf[4][16 * 32];
  int tid = threadIdx.x;
  int lane = tid & 63;
  int w = tid >> 6;                     // wave 0..3
  int qb = blockIdx.x;                  // 0..35 : 64-q-row tile
  int by = blockIdx.y;                  // 0..31
  int s = by & 1, bh = by >> 1;
  int h = bh & (NHEADS - 1);

  for (int t = tid; t < TAB; t += 256) tbf[t] = tabT[h * TAB + t];

  int g = lane >> 4, c = lane & 15;
  int q0 = qb * 64 + w * 16;
  size_t rowbase = (size_t)bh * NSEQ;

  // A-frags for Q (A[m=lane&15][k=(lane>>4)*8+j])
  short8 qh = *(const short8*)&qhi[(rowbase + q0 + c) * HDIM + g * 8];
  short8 ql = *(const short8*)&qlo[(rowbase + q0 + c) * HDIM + g * 8];
  __syncthreads();

  float M[4], Lp[4];
  f32x4 o0 = {0.f, 0.f, 0.f, 0.f}, o1 = {0.f, 0.f, 0.f, 0.f};
#pragma unroll
  for (int r = 0; r < 4; ++r) { M[r] = -INFINITY; Lp[r] = 0.f; }
  ushort* pb = pbuf[w];

  for (int mt = s * MSP; mt < s * MSP + MSP; mt += 32) {
    // ---- QK^T : two 16-kr tiles ----
    short8 b0h = *(const short8*)&khi[(rowbase + mt + c) * HDIM + g * 8];
    short8 b0l = *(const short8*)&klo[(rowbase + mt + c) * HDIM + g * 8];
    short8 b1h = *(const short8*)&khi[(rowbase + mt + 16 + c) * HDIM + g * 8];
    short8 b1l = *(const short8*)&klo[(rowbase + mt + 16 + c) * HDIM + g * 8];
    f32x4 s0 = {0.f, 0.f, 0.f, 0.f}, s1 = {0.f, 0.f, 0.f, 0.f};
    s0 = MFMA16(qh, b0h, s0);
    s1 = MFMA16(qh, b1h, s1);
    s0 = MFMA16(ql, b0h, s0);
    s1 = MFMA16(ql, b1h, s1);
    s0 = MFMA16(qh, b0l, s0);
    s1 = MFMA16(qh, b1l, s1);

    // ---- bias add (C-layout: row=g*4+r, col=c) ----
    float sc0[4], sc1[4];
#pragma unroll
    for (int r = 0; r < 4; ++r) {
      int q = q0 + g * 4 + r;
      int i0 = idx[(size_t)q * NSEQ + mt + c];
      int i1 = idx[(size_t)q * NSEQ + mt + 16 + c];
      sc0[r] = s0[r] + tbf[i0];
      sc1[r] = s1[r] + tbf[i1];
    }

    // ---- online softmax (row reductions across the 16-lane group) ----
#pragma unroll
    for (int r = 0; r < 4; ++r) {
      float mx = fmaxf(sc0[r], sc1[r]);
      mx = fmaxf(mx, __shfl_xor(mx, 1));
      mx = fmaxf(mx, __shfl_xor(mx, 2));
      mx = fmaxf(mx, __shfl_xor(mx, 4));
      mx = fmaxf(mx, __shfl_xor(mx, 8));
      if (mx > M[r]) {
        float alpha = __expf(M[r] - mx);   // first chunk: exp(-inf)=0 zeroes state
        Lp[r] *= alpha;
        o0[r] *= alpha;
        o1[r] *= alpha;
        M[r] = mx;
      }
      float p0 = __expf(sc0[r] - M[r]);
      float p1 = __expf(sc1[r] - M[r]);
      Lp[r] += p0 + p1;
      pb[(g * 4 + r) * 32 + c]      = f2bf(p0);
      pb[(g * 4 + r) * 32 + 16 + c] = f2bf(p1);
    }

    // ---- P: C-layout -> A-layout via LDS (in-wave, in-order DS + waitcnt) ----
    asm volatile("s_waitcnt lgkmcnt(0)" ::: "memory");
    short8 pf = *(const short8*)&pb[c * 32 + g * 8];

    // ---- PV : two 16-d tiles, B[n=d][k=m] from vT[d][m] ----
    short8 vf0 = *(const short8*)&vT[((size_t)(bh * HDIM + c)) * NSEQ + mt + g * 8];
    short8 vf1 = *(const short8*)&vT[((size_t)(bh * HDIM + 16 + c)) * NSEQ + mt + g * 8];
    o0 = MFMA16(pf, vf0, o0);
    o1 = MFMA16(pf, vf1, o1);
  }

  // ---- final L reduce across group, write partials ----
#pragma unroll
  for (int r = 0; r < 4; ++r) {
    float l = Lp[r];
    l += __shfl_xor(l, 1);
    l += __shfl_xor(l, 2);
    l += __shfl_xor(l, 4);
    l += __shfl_xor(l, 8);
    Lp[r] = l;
  }
  size_t prow0 = (size_t)s * RTOT + rowbase + q0;
#pragma unroll
  for (int r = 0; r < 4; ++r) {
    size_t pr = prow0 + g * 4 + r;
    pO[pr * HDIM + c]      = o0[r];
    pO[pr * HDIM + 16 + c] = o1[r];
    if (c == 0) { pM[pr] = M[r]; pL[pr] = Lp[r]; }
  }
}

// ---------------- merge m-splits, write (b,n,h*d) layout for proj ----------------
__global__ void merge_kernel(const float* __restrict__ pO, const float* __restrict__ pM,
                             const float* __restrict__ pL, float* __restrict__ ao) {
  int r = blockIdx.x * 256 + threadIdx.x;
  if (r >= RTOT) return;
  float M = -INFINITY;
#pragma unroll
  for (int sp = 0; sp < SPLITS; ++sp) M = fmaxf(M, pM[(size_t)sp * RTOT + r]);
  float w[SPLITS]; float L = 0.f;
#pragma unroll
  for (int sp = 0; sp < SPLITS; ++sp) {
    w[sp] = __expf(pM[(size_t)sp * RTOT + r] - M);
    L = fmaf(pL[(size_t)sp * RTOT + r], w[sp], L);
  }
  float inv = 1.f / L;
  int n = r % NSEQ; int bh = r / NSEQ; int h = bh % NHEADS; int b = bh / NHEADS;
  float* dst = ao + (size_t)(b * NSEQ + n) * DIMC + h * HDIM;
#pragma unroll
  for (int i = 0; i < HDIM; ++i) {
    float acc = 0.f;
#pragma unroll
    for (int sp = 0; sp < SPLITS; ++sp)
      acc = fmaf(pO[((size_t)sp * RTOT + r) * HDIM + i], w[sp], acc);
    dst[i] = acc * inv;
  }
}

extern "C" void kernel_launch(void* const* d_in, const int* in_sizes, int n_in,
                              void* d_out, int out_size, void* d_ws, size_t ws_size,
                              hipStream_t stream) {
  const float* x    = (const float*)d_in[0];
  const int*   idx  = (const int*)d_in[1];
  const float* tbl  = (const float*)d_in[2];
  const float* sls  = (const float*)d_in[3];
  const float* Wqkv = (const float*)d_in[5];
  const float* bqkv = (const float*)d_in[6];
  const float* temp = (const float*)d_in[7];
  const float* qe   = (const float*)d_in[8];
  const float* Wp   = (const float*)d_in[9];
  const float* bp   = (const float*)d_in[10];
  const float* W1   = (const float*)d_in[11];
  const float* b1   = (const float*)d_in[12];
  const float* W2   = (const float*)d_in[13];
  const float* b2   = (const float*)d_in[14];

  float* ws   = (float*)d_ws;
  float* tabT = ws;                        // 72,256
  float* qkv  = tabT + 72256;              // 3,538,944
  float* ao   = qkv + 3538944;             // 1,179,648
  float* pO   = ao + 1179648;              // 2*36864*32 = 2,359,296
  float* pM   = pO + 2359296;              // 73,728
  float* pL   = pM + 73728;                // 73,728
  ushort* qhi = (ushort*)(pL + 73728);     // RTOT*32 u16 each = 589,824 floats
  ushort* qlo = qhi + (size_t)RTOT * HDIM;
  ushort* khi = qlo + (size_t)RTOT * HDIM;
  ushort* klo = khi + (size_t)RTOT * HDIM;
  ushort* vT  = klo + (size_t)RTOT * HDIM; // [16][32][2304] u16
  float* out  = (float*)d_out;

  cpb_kernel<<<dim3((TAB + 255) / 256), dim3(256), 0, stream>>>(tbl, W1, b1, W2, b2, tabT);
  gemm_tn<<<dim3(12, 72), dim3(256), 0, stream>>>(x, Wqkv, bqkv, qkv, BB * NSEQ, 3 * DIMC, DIMC);
  prep_kernel<<<dim3(RTOT / 256), dim3(256), 0, stream>>>(qkv, temp, sls, qe, qhi, qlo, khi, klo, vT);
  attn_kernel<<<dim3(NSEQ / 64, BB * NHEADS * SPLITS), dim3(256), 0, stream>>>(
      qhi, qlo, khi, klo, vT, tabT, idx, pO, pM, pL);
  merge_kernel<<<dim3(RTOT / 256), dim3(256), 0, stream>>>(pO, pM, pL, ao);
  gemm_tn<<<dim3(4, 72), dim3(256), 0, stream>>>(ao, Wp, bp, out, BB * NSEQ, DIMC, DIMC);
}

// Round 4
// 290.285 us; speedup vs baseline: 2.0748x; 1.2136x over previous
//
#include <hip/hip_runtime.h>
#include <math.h>

#define DIMC 256
#define NHEADS 8
#define HDIM 32
#define CPBH 512
#define BB 2
#define NSEQ 2304
#define TAB 9025
#define RTOT (BB*NHEADS*NSEQ)      // 36864
#define SPLITS 2
#define MSP (NSEQ/SPLITS)          // 1152 m per split

#define NX  (BB*NSEQ*DIMC)         // 1,179,648  x elems
#define NWQ (3*DIMC*DIMC)          // 196,608    Wqkv elems
#define NWP (DIMC*DIMC)            // 65,536     Wproj elems

typedef unsigned short ushort;
typedef __attribute__((ext_vector_type(8))) short short8;
typedef __attribute__((ext_vector_type(4))) float f32x4;

#define MFMA16(a,b,c) __builtin_amdgcn_mfma_f32_16x16x32_bf16((a),(b),(c),0,0,0)

__device__ __forceinline__ ushort f2bf(float x) {          // RNE fp32->bf16
  unsigned u = __float_as_uint(x);
  u += 0x7FFFu + ((u >> 16) & 1u);
  return (ushort)(u >> 16);
}
__device__ __forceinline__ float bf2f(ushort b) {
  return __uint_as_float(((unsigned)b) << 16);
}

// ---------------- split fp32 -> (hi,lo) bf16 planes for x, Wqkv, Wproj ----------------
__global__ void split_kernel(const float* __restrict__ x, const float* __restrict__ wq,
                             const float* __restrict__ wp,
                             ushort* __restrict__ xh, ushort* __restrict__ xl,
                             ushort* __restrict__ wqh, ushort* __restrict__ wql,
                             ushort* __restrict__ wph, ushort* __restrict__ wpl) {
  int i = blockIdx.x * 256 + threadIdx.x;
  const float* src; ushort *hi, *lo; int j;
  if (i < NX)            { src = x;  hi = xh;  lo = xl;  j = i; }
  else if (i < NX + NWQ) { src = wq; hi = wqh; lo = wql; j = i - NX; }
  else                   { src = wp; hi = wph; lo = wpl; j = i - NX - NWQ; }
  float v = src[j];
  ushort h = f2bf(v);
  hi[j] = h;
  lo[j] = f2bf(v - bf2f(h));
}

// ---------------- CPB MLP: tabBf[h][t] (bf16), j-parallel x4 ----------------
__global__ void cpb_kernel(const float* __restrict__ tbl, const float* __restrict__ W1,
                           const float* __restrict__ b1, const float* __restrict__ W2,
                           const float* __restrict__ b2, ushort* __restrict__ tabBf) {
  __shared__ float part[4][64][NHEADS];
  int tl = threadIdx.x & 63, jc = threadIdx.x >> 6;
  int t = blockIdx.x * 64 + tl;
  bool valid = t < TAB;
  float c0 = 0.f, c1 = 0.f;
  if (valid) { c0 = tbl[2*t]; c1 = tbl[2*t+1]; }
  float acc[NHEADS];
#pragma unroll
  for (int h = 0; h < NHEADS; ++h) acc[h] = 0.f;
  for (int j = jc * 128; j < jc * 128 + 128; ++j) {
    float hid = fmaxf(fmaf(c0, W1[2*j], fmaf(c1, W1[2*j+1], b1[j])), 0.f);
#pragma unroll
    for (int h = 0; h < NHEADS; ++h) acc[h] = fmaf(hid, W2[h*CPBH + j], acc[h]);
  }
#pragma unroll
  for (int h = 0; h < NHEADS; ++h) part[jc][tl][h] = acc[h];
  __syncthreads();
  if (jc == 0 && valid) {
#pragma unroll
    for (int h = 0; h < NHEADS; ++h) {
      float s = part[0][tl][h] + part[1][tl][h] + part[2][tl][h] + part[3][tl][h] + b2[h];
      tabBf[h*TAB + t] = f2bf(s);
    }
  }
}

// ------- split-bf16 MFMA GEMM: C[M,Nn] = A@W^T + bias; A,W as hi/lo planes, rows x K -------
__launch_bounds__(256)
__global__ void gemm_mfma(const ushort* __restrict__ Ah, const ushort* __restrict__ Al,
                          const ushort* __restrict__ Bh, const ushort* __restrict__ Bl,
                          const float* __restrict__ bias, float* __restrict__ C,
                          int Nn, int K) {
  int tid = threadIdx.x;
  int lane = tid & 63;
  int w = tid >> 6;
  int g = lane >> 4, c = lane & 15;
  int n0 = blockIdx.x * 64;
  int m0 = blockIdx.y * 64 + w * 16;
  f32x4 acc[4] = {{0,0,0,0},{0,0,0,0},{0,0,0,0},{0,0,0,0}};
#pragma unroll 2
  for (int k0 = 0; k0 < K; k0 += 32) {
    short8 ah = *(const short8*)&Ah[(size_t)(m0 + c) * K + k0 + g * 8];
    short8 al = *(const short8*)&Al[(size_t)(m0 + c) * K + k0 + g * 8];
#pragma unroll
    for (int nt = 0; nt < 4; ++nt) {
      short8 bh = *(const short8*)&Bh[(size_t)(n0 + nt * 16 + c) * K + k0 + g * 8];
      short8 bl = *(const short8*)&Bl[(size_t)(n0 + nt * 16 + c) * K + k0 + g * 8];
      acc[nt] = MFMA16(ah, bh, acc[nt]);
      acc[nt] = MFMA16(al, bh, acc[nt]);
      acc[nt] = MFMA16(ah, bl, acc[nt]);
    }
  }
#pragma unroll
  for (int nt = 0; nt < 4; ++nt) {
    float bv = bias[n0 + nt * 16 + c];
#pragma unroll
    for (int r = 0; r < 4; ++r) {
      C[(size_t)(m0 + g * 4 + r) * Nn + n0 + nt * 16 + c] = acc[nt][r] + bv;
    }
  }
}

// ------- prep: qkv -> split-bf16 qhi/qlo/khi/klo [row][32], bf16 vT [bh][d][m] -------
__global__ void prep_kernel(const float* __restrict__ qkv, const float* __restrict__ temp,
                            const float* __restrict__ sls, const float* __restrict__ qe,
                            ushort* __restrict__ qhi, ushort* __restrict__ qlo,
                            ushort* __restrict__ khi, ushort* __restrict__ klo,
                            ushort* __restrict__ vT) {
  int r = blockIdx.x * 256 + threadIdx.x;
  if (r >= RTOT) return;
  int n = r % NSEQ; int bh = r / NSEQ; int h = bh % NHEADS; int b = bh / NHEADS;
  const float* base = qkv + (size_t)(b * NSEQ + n) * (3 * DIMC);
  float q[HDIM], k[HDIM], vl[HDIM];
#pragma unroll
  for (int i = 0; i < HDIM; i += 4) {
    *(float4*)&q[i]  = *(const float4*)&base[h * HDIM + i];
    *(float4*)&k[i]  = *(const float4*)&base[DIMC + h * HDIM + i];
    *(float4*)&vl[i] = *(const float4*)&base[2 * DIMC + h * HDIM + i];
  }
  float sq = 0.f, sk = 0.f;
#pragma unroll
  for (int i = 0; i < HDIM; ++i) { sq = fmaf(q[i], q[i], sq); sk = fmaf(k[i], k[i], sk); }
  float invq = 1.f / fmaxf(sqrtf(sq), 1e-12f);
  float invk = 1.f / fmaxf(sqrtf(sk), 1e-12f);
  float scale = log1pf(expf(temp[h])) * sls[0];
  size_t o = (size_t)r * HDIM;
#pragma unroll
  for (int i = 0; i < HDIM; ++i) {
    float qs = (q[i] * invq + qe[h*HDIM + i]) * scale;
    ushort qh = f2bf(qs);
    qhi[o + i] = qh;
    qlo[o + i] = f2bf(qs - bf2f(qh));
    float ks = k[i] * invk;
    ushort kh = f2bf(ks);
    khi[o + i] = kh;
    klo[o + i] = f2bf(ks - bf2f(kh));
    vT[((size_t)(bh * HDIM + i)) * NSEQ + n] = f2bf(vl[i]);
  }
}

// ------- MFMA flash attention, NO-MAX softmax (scores statically bounded |s|<~56) -------
__launch_bounds__(256)
__global__ void attn_kernel(const ushort* __restrict__ qhi, const ushort* __restrict__ qlo,
                            const ushort* __restrict__ khi, const ushort* __restrict__ klo,
                            const ushort* __restrict__ vT, const ushort* __restrict__ tabBf,
                            const int* __restrict__ idx,
                            float* __restrict__ pO, float* __restrict__ pL) {
  __shared__ __align__(16) ushort pbuf[4][16 * 32];  // 4 KB
  __shared__ ushort tbf[TAB + 1];                    // 18 KB bf16 bias table
  int tid = threadIdx.x;
  int lane = tid & 63;
  int w = tid >> 6;                     // wave 0..3
  int qb = blockIdx.x;                  // 0..35 : 64-q-row tile
  int by = blockIdx.y;                  // 0..31
  int s = by & 1, bh = by >> 1;
  int h = bh & (NHEADS - 1);

  for (int t = tid; t < TAB; t += 256) tbf[t] = tabBf[h * TAB + t];

  int g = lane >> 4, c = lane & 15;
  int q0 = qb * 64 + w * 16;
  size_t rowbase = (size_t)bh * NSEQ;

  short8 qh = *(const short8*)&qhi[(rowbase + q0 + c) * HDIM + g * 8];
  short8 ql = *(const short8*)&qlo[(rowbase + q0 + c) * HDIM + g * 8];
  __syncthreads();

  float Lp[4] = {0.f, 0.f, 0.f, 0.f};
  f32x4 o0 = {0.f, 0.f, 0.f, 0.f}, o1 = {0.f, 0.f, 0.f, 0.f};
  ushort* pb = pbuf[w];

  for (int mt = s * MSP; mt < s * MSP + MSP; mt += 32) {
    // ---- QK^T : two 16-kr tiles, split-bf16 (3 MFMA each) ----
    short8 b0h = *(const short8*)&khi[(rowbase + mt + c) * HDIM + g * 8];
    short8 b0l = *(const short8*)&klo[(rowbase + mt + c) * HDIM + g * 8];
    short8 b1h = *(const short8*)&khi[(rowbase + mt + 16 + c) * HDIM + g * 8];
    short8 b1l = *(const short8*)&klo[(rowbase + mt + 16 + c) * HDIM + g * 8];
    f32x4 s0 = {0.f, 0.f, 0.f, 0.f}, s1 = {0.f, 0.f, 0.f, 0.f};
    s0 = MFMA16(qh, b0h, s0);
    s1 = MFMA16(qh, b1h, s1);
    s0 = MFMA16(ql, b0h, s0);
    s1 = MFMA16(ql, b1h, s1);
    s0 = MFMA16(qh, b0l, s0);
    s1 = MFMA16(qh, b1l, s1);

    // ---- bias add + exp (no max subtraction; branch-free, pipelines freely) ----
#pragma unroll
    for (int r = 0; r < 4; ++r) {
      int q = q0 + g * 4 + r;
      int i0 = idx[(size_t)q * NSEQ + mt + c];
      int i1 = idx[(size_t)q * NSEQ + mt + 16 + c];
      float p0 = __expf(s0[r] + bf2f(tbf[i0]));
      float p1 = __expf(s1[r] + bf2f(tbf[i1]));
      Lp[r] += p0 + p1;
      pb[(g * 4 + r) * 32 + c]      = f2bf(p0);
      pb[(g * 4 + r) * 32 + 16 + c] = f2bf(p1);
    }

    // ---- P: C-layout -> A-layout via LDS roundtrip ----
    asm volatile("s_waitcnt lgkmcnt(0)" ::: "memory");
    short8 pf = *(const short8*)&pb[c * 32 + g * 8];

    // ---- PV : two 16-d tiles ----
    short8 vf0 = *(const short8*)&vT[((size_t)(bh * HDIM + c)) * NSEQ + mt + g * 8];
    short8 vf1 = *(const short8*)&vT[((size_t)(bh * HDIM + 16 + c)) * NSEQ + mt + g * 8];
    o0 = MFMA16(pf, vf0, o0);
    o1 = MFMA16(pf, vf1, o1);
  }

  // ---- L row-sums across the 16-lane group ----
#pragma unroll
  for (int r = 0; r < 4; ++r) {
    float l = Lp[r];
    l += __shfl_xor(l, 1);
    l += __shfl_xor(l, 2);
    l += __shfl_xor(l, 4);
    l += __shfl_xor(l, 8);
    Lp[r] = l;
  }
  size_t prow0 = (size_t)s * RTOT + rowbase + q0;
#pragma unroll
  for (int r = 0; r < 4; ++r) {
    size_t pr = prow0 + g * 4 + r;
    pO[pr * HDIM + c]      = o0[r];
    pO[pr * HDIM + 16 + c] = o1[r];
    if (c == 0) pL[pr] = Lp[r];
  }
}

// ------- merge splits (plain sums), normalize, emit split-bf16 ao for proj GEMM -------
__global__ void merge_kernel(const float* __restrict__ pO, const float* __restrict__ pL,
                             ushort* __restrict__ aoh, ushort* __restrict__ aol) {
  int r = blockIdx.x * 256 + threadIdx.x;
  if (r >= RTOT) return;
  float L = 0.f;
#pragma unroll
  for (int sp = 0; sp < SPLITS; ++sp) L += pL[(size_t)sp * RTOT + r];
  float inv = 1.f / L;
  int n = r % NSEQ; int bh = r / NSEQ; int h = bh % NHEADS; int b = bh / NHEADS;
  size_t dst = (size_t)(b * NSEQ + n) * DIMC + h * HDIM;
#pragma unroll
  for (int i = 0; i < HDIM; ++i) {
    float acc = 0.f;
#pragma unroll
    for (int sp = 0; sp < SPLITS; ++sp)
      acc += pO[((size_t)sp * RTOT + r) * HDIM + i];
    float v = acc * inv;
    ushort hh = f2bf(v);
    aoh[dst + i] = hh;
    aol[dst + i] = f2bf(v - bf2f(hh));
  }
}

extern "C" void kernel_launch(void* const* d_in, const int* in_sizes, int n_in,
                              void* d_out, int out_size, void* d_ws, size_t ws_size,
                              hipStream_t stream) {
  const float* x    = (const float*)d_in[0];
  const int*   idx  = (const int*)d_in[1];
  const float* tbl  = (const float*)d_in[2];
  const float* sls  = (const float*)d_in[3];
  const float* Wqkv = (const float*)d_in[5];
  const float* bqkv = (const float*)d_in[6];
  const float* temp = (const float*)d_in[7];
  const float* qe   = (const float*)d_in[8];
  const float* Wp   = (const float*)d_in[9];
  const float* bp   = (const float*)d_in[10];
  const float* W1   = (const float*)d_in[11];
  const float* b1   = (const float*)d_in[12];
  const float* W2   = (const float*)d_in[13];
  const float* b2   = (const float*)d_in[14];

  float* ws   = (float*)d_ws;
  float* qkv  = ws;                        // 3,538,944 f
  float* pO   = qkv + 3538944;             // 2,359,296 f
  float* pL   = pO + 2359296;              // 73,728 f
  ushort* u   = (ushort*)(pL + 73728);
  ushort* qhi = u;                u += (size_t)RTOT * HDIM;   // 1,179,648 each
  ushort* qlo = u;                u += (size_t)RTOT * HDIM;
  ushort* khi = u;                u += (size_t)RTOT * HDIM;
  ushort* klo = u;                u += (size_t)RTOT * HDIM;
  ushort* vT  = u;                u += (size_t)RTOT * HDIM;
  ushort* xh  = u;                u += NX;
  ushort* xl  = u;                u += NX;
  ushort* wqh = u;                u += NWQ;
  ushort* wql = u;                u += NWQ;
  ushort* wph = u;                u += NWP;
  ushort* wpl = u;                u += NWP;
  ushort* aoh = u;                u += (size_t)RTOT * HDIM;
  ushort* aol = u;                u += (size_t)RTOT * HDIM;
  ushort* tabBf = u;              u += 9216;
  float* out  = (float*)d_out;

  split_kernel<<<dim3((NX + NWQ + NWP) / 256), dim3(256), 0, stream>>>(
      x, Wqkv, Wp, xh, xl, wqh, wql, wph, wpl);
  cpb_kernel<<<dim3((TAB + 63) / 64), dim3(256), 0, stream>>>(tbl, W1, b1, W2, b2, tabBf);
  gemm_mfma<<<dim3(12, 72), dim3(256), 0, stream>>>(xh, xl, wqh, wql, bqkv, qkv, 3 * DIMC, DIMC);
  prep_kernel<<<dim3(RTOT / 256), dim3(256), 0, stream>>>(qkv, temp, sls, qe, qhi, qlo, khi, klo, vT);
  attn_kernel<<<dim3(NSEQ / 64, BB * NHEADS * SPLITS), dim3(256), 0, stream>>>(
      qhi, qlo, khi, klo, vT, tabBf, idx, pO, pL);
  merge_kernel<<<dim3(RTOT / 256), dim3(256), 0, stream>>>(pO, pL, aoh, aol);
  gemm_mfma<<<dim3(4, 72), dim3(256), 0, stream>>>(aoh, aol, wph, wpl, bp, out, DIMC, DIMC);
}

// Round 5
// 281.195 us; speedup vs baseline: 2.1419x; 1.0323x over previous
//
#include <hip/hip_runtime.h>
#include <math.h>

#define DIMC 256
#define NHEADS 8
#define HDIM 32
#define CPBH 512
#define BB 2
#define NSEQ 2304
#define TAB 9025
#define RTOT (BB*NHEADS*NSEQ)      // 36864
#define SPLITS 4
#define MSP (NSEQ/SPLITS)          // 576 m per split
#define PBS 36                     // pbuf row stride in u16 (18 words: conflict-free writes)

#define NX  (BB*NSEQ*DIMC)         // 1,179,648
#define NWQ (3*DIMC*DIMC)          // 196,608
#define NWP (DIMC*DIMC)            // 65,536

typedef unsigned short ushort;
typedef __attribute__((ext_vector_type(8))) short short8;
typedef __attribute__((ext_vector_type(4))) short short4v;
typedef __attribute__((ext_vector_type(4))) float f32x4;

#define MFMA16(a,b,c) __builtin_amdgcn_mfma_f32_16x16x32_bf16((a),(b),(c),0,0,0)

__device__ __forceinline__ ushort f2bf(float x) {          // RNE fp32->bf16
  unsigned u = __float_as_uint(x);
  u += 0x7FFFu + ((u >> 16) & 1u);
  return (ushort)(u >> 16);
}
__device__ __forceinline__ float bf2f(ushort b) {
  return __uint_as_float(((unsigned)b) << 16);
}

// ---------------- split fp32 -> (hi,lo) bf16 planes for x, Wqkv, Wproj ----------------
__global__ void split_kernel(const float* __restrict__ x, const float* __restrict__ wq,
                             const float* __restrict__ wp,
                             ushort* __restrict__ xh, ushort* __restrict__ xl,
                             ushort* __restrict__ wqh, ushort* __restrict__ wql,
                             ushort* __restrict__ wph, ushort* __restrict__ wpl) {
  int i = blockIdx.x * 256 + threadIdx.x;
  const float* src; ushort *hi, *lo; int j;
  if (i < NX)            { src = x;  hi = xh;  lo = xl;  j = i; }
  else if (i < NX + NWQ) { src = wq; hi = wqh; lo = wql; j = i - NX; }
  else                   { src = wp; hi = wph; lo = wpl; j = i - NX - NWQ; }
  float v = src[j];
  ushort h = f2bf(v);
  hi[j] = h;
  lo[j] = f2bf(v - bf2f(h));
}

// ---------------- CPB MLP: tabBf[h][t] (bf16), j-parallel x8 ----------------
__global__ void cpb_kernel(const float* __restrict__ tbl, const float* __restrict__ W1,
                           const float* __restrict__ b1, const float* __restrict__ W2,
                           const float* __restrict__ b2, ushort* __restrict__ tabBf) {
  __shared__ float part[8][64][NHEADS];
  int tl = threadIdx.x & 63, jc = threadIdx.x >> 6;   // 8 j-chunks of 64
  int t = blockIdx.x * 64 + tl;
  bool valid = t < TAB;
  float c0 = 0.f, c1 = 0.f;
  if (valid) { c0 = tbl[2*t]; c1 = tbl[2*t+1]; }
  float acc[NHEADS];
#pragma unroll
  for (int h = 0; h < NHEADS; ++h) acc[h] = 0.f;
  for (int j = jc * 64; j < jc * 64 + 64; ++j) {
    float hid = fmaxf(fmaf(c0, W1[2*j], fmaf(c1, W1[2*j+1], b1[j])), 0.f);
#pragma unroll
    for (int h = 0; h < NHEADS; ++h) acc[h] = fmaf(hid, W2[h*CPBH + j], acc[h]);
  }
#pragma unroll
  for (int h = 0; h < NHEADS; ++h) part[jc][tl][h] = acc[h];
  __syncthreads();
  if (jc == 0 && valid) {
#pragma unroll
    for (int h = 0; h < NHEADS; ++h) {
      float s = b2[h];
#pragma unroll
      for (int p = 0; p < 8; ++p) s += part[p][tl][h];
      tabBf[h*TAB + t] = f2bf(s);
    }
  }
}

// ------- split-bf16 MFMA GEMM: C[M,Nn] = A@W^T + bias -------
__launch_bounds__(256)
__global__ void gemm_mfma(const ushort* __restrict__ Ah, const ushort* __restrict__ Al,
                          const ushort* __restrict__ Bh, const ushort* __restrict__ Bl,
                          const float* __restrict__ bias, float* __restrict__ C,
                          int Nn, int K) {
  int tid = threadIdx.x;
  int lane = tid & 63;
  int w = tid >> 6;
  int g = lane >> 4, c = lane & 15;
  int n0 = blockIdx.x * 64;
  int m0 = blockIdx.y * 64 + w * 16;
  f32x4 acc[4] = {{0,0,0,0},{0,0,0,0},{0,0,0,0},{0,0,0,0}};
#pragma unroll 2
  for (int k0 = 0; k0 < K; k0 += 32) {
    short8 ah = *(const short8*)&Ah[(size_t)(m0 + c) * K + k0 + g * 8];
    short8 al = *(const short8*)&Al[(size_t)(m0 + c) * K + k0 + g * 8];
#pragma unroll
    for (int nt = 0; nt < 4; ++nt) {
      short8 bh = *(const short8*)&Bh[(size_t)(n0 + nt * 16 + c) * K + k0 + g * 8];
      short8 bl = *(const short8*)&Bl[(size_t)(n0 + nt * 16 + c) * K + k0 + g * 8];
      acc[nt] = MFMA16(ah, bh, acc[nt]);
      acc[nt] = MFMA16(al, bh, acc[nt]);
      acc[nt] = MFMA16(ah, bl, acc[nt]);
    }
  }
#pragma unroll
  for (int nt = 0; nt < 4; ++nt) {
    float bv = bias[n0 + nt * 16 + c];
#pragma unroll
    for (int r = 0; r < 4; ++r) {
      C[(size_t)(m0 + g * 4 + r) * Nn + n0 + nt * 16 + c] = acc[nt][r] + bv;
    }
  }
}

// ------- prep: qkv -> split-bf16 q/k planes, bf16 vT with interleave permutation baked -------
// vT chunk layout: within each 32-m chunk, position p holds m-col (p>>1) + 16*(p&1),
// matching the pbuf interleaved-pair order so PV's MFMA k-sum permutation cancels.
__global__ void prep_kernel(const float* __restrict__ qkv, const float* __restrict__ temp,
                            const float* __restrict__ sls, const float* __restrict__ qe,
                            ushort* __restrict__ qhi, ushort* __restrict__ qlo,
                            ushort* __restrict__ khi, ushort* __restrict__ klo,
                            ushort* __restrict__ vT) {
  int r = blockIdx.x * 256 + threadIdx.x;
  if (r >= RTOT) return;
  int n = r % NSEQ; int bh = r / NSEQ; int h = bh % NHEADS; int b = bh / NHEADS;
  const float* base = qkv + (size_t)(b * NSEQ + n) * (3 * DIMC);
  float q[HDIM], k[HDIM], vl[HDIM];
#pragma unroll
  for (int i = 0; i < HDIM; i += 4) {
    *(float4*)&q[i]  = *(const float4*)&base[h * HDIM + i];
    *(float4*)&k[i]  = *(const float4*)&base[DIMC + h * HDIM + i];
    *(float4*)&vl[i] = *(const float4*)&base[2 * DIMC + h * HDIM + i];
  }
  float sq = 0.f, sk = 0.f;
#pragma unroll
  for (int i = 0; i < HDIM; ++i) { sq = fmaf(q[i], q[i], sq); sk = fmaf(k[i], k[i], sk); }
  float invq = 1.f / fmaxf(sqrtf(sq), 1e-12f);
  float invk = 1.f / fmaxf(sqrtf(sk), 1e-12f);
  float scale = log1pf(expf(temp[h])) * sls[0];
  // permuted column position for vT
  int mm = n & 31;
  int np = (n & ~31) + 2 * (mm & 15) + (mm >> 4);
  size_t o = (size_t)r * HDIM;
#pragma unroll
  for (int i = 0; i < HDIM; ++i) {
    float qs = (q[i] * invq + qe[h*HDIM + i]) * scale;
    ushort qh = f2bf(qs);
    qhi[o + i] = qh;
    qlo[o + i] = f2bf(qs - bf2f(qh));
    float ks = k[i] * invk;
    ushort kh = f2bf(ks);
    khi[o + i] = kh;
    klo[o + i] = f2bf(ks - bf2f(kh));
    vT[((size_t)(bh * HDIM + i)) * NSEQ + np] = f2bf(vl[i]);
  }
}

// ------- MFMA flash attention, no-max softmax, interleaved pbuf, SPLITS=4 -------
__launch_bounds__(256)
__global__ void attn_kernel(const ushort* __restrict__ qhi, const ushort* __restrict__ qlo,
                            const ushort* __restrict__ khi, const ushort* __restrict__ klo,
                            const ushort* __restrict__ vT, const ushort* __restrict__ tabBf,
                            const int* __restrict__ idx,
                            float* __restrict__ pO, float* __restrict__ pL) {
  __shared__ __align__(16) ushort pbuf[4][16 * PBS];  // 4*1152 B
  __shared__ ushort tbf[TAB + 3];                     // ~18 KB bf16 bias table
  int tid = threadIdx.x;
  int lane = tid & 63;
  int w = tid >> 6;                     // wave 0..3
  int qb = blockIdx.x;                  // 0..35 : 64-q-row tile
  int by = blockIdx.y;                  // 0..63
  int s = by & 3, bh = by >> 2;
  int h = bh & (NHEADS - 1);

  for (int t = tid; t < TAB; t += 256) tbf[t] = tabBf[h * TAB + t];

  int g = lane >> 4, c = lane & 15;
  int q0 = qb * 64 + w * 16;
  size_t rowbase = (size_t)bh * NSEQ;

  short8 qh = *(const short8*)&qhi[(rowbase + q0 + c) * HDIM + g * 8];
  short8 ql = *(const short8*)&qlo[(rowbase + q0 + c) * HDIM + g * 8];
  __syncthreads();

  float Lp[4] = {0.f, 0.f, 0.f, 0.f};
  f32x4 o0 = {0.f, 0.f, 0.f, 0.f}, o1 = {0.f, 0.f, 0.f, 0.f};
  ushort* pb = pbuf[w];

  for (int mt = s * MSP; mt < s * MSP + MSP; mt += 32) {
    // ---- QK^T : two 16-kr tiles, split-bf16 ----
    short8 b0h = *(const short8*)&khi[(rowbase + mt + c) * HDIM + g * 8];
    short8 b0l = *(const short8*)&klo[(rowbase + mt + c) * HDIM + g * 8];
    short8 b1h = *(const short8*)&khi[(rowbase + mt + 16 + c) * HDIM + g * 8];
    short8 b1l = *(const short8*)&klo[(rowbase + mt + 16 + c) * HDIM + g * 8];
    f32x4 s0 = {0.f, 0.f, 0.f, 0.f}, s1 = {0.f, 0.f, 0.f, 0.f};
    s0 = MFMA16(qh, b0h, s0);
    s1 = MFMA16(qh, b1h, s1);
    s0 = MFMA16(ql, b0h, s0);
    s1 = MFMA16(ql, b1h, s1);
    s0 = MFMA16(qh, b0l, s0);
    s1 = MFMA16(qh, b1l, s1);

    // ---- bias + exp; pack (p0,p1) pairs -> one u32 LDS write (interleaved layout) ----
#pragma unroll
    for (int r = 0; r < 4; ++r) {
      int q = q0 + g * 4 + r;
      int i0 = idx[(size_t)q * NSEQ + mt + c];
      int i1 = idx[(size_t)q * NSEQ + mt + 16 + c];
      float p0 = __expf(s0[r] + bf2f(tbf[i0]));
      float p1 = __expf(s1[r] + bf2f(tbf[i1]));
      Lp[r] += p0 + p1;
      unsigned pk = (unsigned)f2bf(p0) | ((unsigned)f2bf(p1) << 16);
      *(unsigned*)&pb[(g * 4 + r) * PBS + 2 * c] = pk;
    }

    // ---- P: C-layout -> A-layout (compiler inserts the DS dependency wait) ----
    short4v pa = *(const short4v*)&pb[c * PBS + g * 8];
    short4v pbv = *(const short4v*)&pb[c * PBS + g * 8 + 4];
    short8 pf = __builtin_shufflevector(pa, pbv, 0, 1, 2, 3, 4, 5, 6, 7);

    // ---- PV : two 16-d tiles (vT pre-permuted to match) ----
    short8 vf0 = *(const short8*)&vT[((size_t)(bh * HDIM + c)) * NSEQ + mt + g * 8];
    short8 vf1 = *(const short8*)&vT[((size_t)(bh * HDIM + 16 + c)) * NSEQ + mt + g * 8];
    o0 = MFMA16(pf, vf0, o0);
    o1 = MFMA16(pf, vf1, o1);
  }

  // ---- L row-sums across the 16-lane group ----
#pragma unroll
  for (int r = 0; r < 4; ++r) {
    float l = Lp[r];
    l += __shfl_xor(l, 1);
    l += __shfl_xor(l, 2);
    l += __shfl_xor(l, 4);
    l += __shfl_xor(l, 8);
    Lp[r] = l;
  }
  size_t prow0 = (size_t)s * RTOT + rowbase + q0;
#pragma unroll
  for (int r = 0; r < 4; ++r) {
    size_t pr = prow0 + g * 4 + r;
    pO[pr * HDIM + c]      = o0[r];
    pO[pr * HDIM + 16 + c] = o1[r];
    if (c == 0) pL[pr] = Lp[r];
  }
}

// ------- merge splits (plain sums), normalize, emit split-bf16 ao for proj GEMM -------
__global__ void merge_kernel(const float* __restrict__ pO, const float* __restrict__ pL,
                             ushort* __restrict__ aoh, ushort* __restrict__ aol) {
  int r = blockIdx.x * 256 + threadIdx.x;
  if (r >= RTOT) return;
  float L = 0.f;
#pragma unroll
  for (int sp = 0; sp < SPLITS; ++sp) L += pL[(size_t)sp * RTOT + r];
  float inv = 1.f / L;
  int n = r % NSEQ; int bh = r / NSEQ; int h = bh % NHEADS; int b = bh / NHEADS;
  size_t dst = (size_t)(b * NSEQ + n) * DIMC + h * HDIM;
#pragma unroll
  for (int i = 0; i < HDIM; i += 4) {
    float4 acc = {0.f, 0.f, 0.f, 0.f};
#pragma unroll
    for (int sp = 0; sp < SPLITS; ++sp) {
      float4 t = *(const float4*)&pO[((size_t)sp * RTOT + r) * HDIM + i];
      acc.x += t.x; acc.y += t.y; acc.z += t.z; acc.w += t.w;
    }
    float vv[4] = {acc.x * inv, acc.y * inv, acc.z * inv, acc.w * inv};
#pragma unroll
    for (int j = 0; j < 4; ++j) {
      ushort hh = f2bf(vv[j]);
      aoh[dst + i + j] = hh;
      aol[dst + i + j] = f2bf(vv[j] - bf2f(hh));
    }
  }
}

extern "C" void kernel_launch(void* const* d_in, const int* in_sizes, int n_in,
                              void* d_out, int out_size, void* d_ws, size_t ws_size,
                              hipStream_t stream) {
  const float* x    = (const float*)d_in[0];
  const int*   idx  = (const int*)d_in[1];
  const float* tbl  = (const float*)d_in[2];
  const float* sls  = (const float*)d_in[3];
  const float* Wqkv = (const float*)d_in[5];
  const float* bqkv = (const float*)d_in[6];
  const float* temp = (const float*)d_in[7];
  const float* qe   = (const float*)d_in[8];
  const float* Wp   = (const float*)d_in[9];
  const float* bp   = (const float*)d_in[10];
  const float* W1   = (const float*)d_in[11];
  const float* b1   = (const float*)d_in[12];
  const float* W2   = (const float*)d_in[13];
  const float* b2   = (const float*)d_in[14];

  float* ws   = (float*)d_ws;
  float* qkv  = ws;                        // 3,538,944 f
  float* pO   = qkv + 3538944;             // 4,718,592 f
  float* pL   = pO + 4718592;              // 147,456 f
  ushort* u   = (ushort*)(pL + 147456);
  ushort* qhi = u;                u += (size_t)RTOT * HDIM;
  ushort* qlo = u;                u += (size_t)RTOT * HDIM;
  ushort* khi = u;                u += (size_t)RTOT * HDIM;
  ushort* klo = u;                u += (size_t)RTOT * HDIM;
  ushort* vT  = u;                u += (size_t)RTOT * HDIM;
  ushort* xh  = u;                u += NX;
  ushort* xl  = u;                u += NX;
  ushort* wqh = u;                u += NWQ;
  ushort* wql = u;                u += NWQ;
  ushort* wph = u;                u += NWP;
  ushort* wpl = u;                u += NWP;
  ushort* aoh = u;                u += (size_t)RTOT * HDIM;
  ushort* aol = u;                u += (size_t)RTOT * HDIM;
  ushort* tabBf = u;              u += 72256;   // NHEADS*TAB = 72,200
  float* out  = (float*)d_out;

  split_kernel<<<dim3((NX + NWQ + NWP) / 256), dim3(256), 0, stream>>>(
      x, Wqkv, Wp, xh, xl, wqh, wql, wph, wpl);
  cpb_kernel<<<dim3((TAB + 63) / 64), dim3(512), 0, stream>>>(tbl, W1, b1, W2, b2, tabBf);
  gemm_mfma<<<dim3(12, 72), dim3(256), 0, stream>>>(xh, xl, wqh, wql, bqkv, qkv, 3 * DIMC, DIMC);
  prep_kernel<<<dim3(RTOT / 256), dim3(256), 0, stream>>>(qkv, temp, sls, qe, qhi, qlo, khi, klo, vT);
  attn_kernel<<<dim3(NSEQ / 64, BB * NHEADS * SPLITS), dim3(256), 0, stream>>>(
      qhi, qlo, khi, klo, vT, tabBf, idx, pO, pL);
  merge_kernel<<<dim3(RTOT / 256), dim3(256), 0, stream>>>(pO, pL, aoh, aol);
  gemm_mfma<<<dim3(4, 72), dim3(256), 0, stream>>>(aoh, aol, wph, wpl, bp, out, DIMC, DIMC);
}